// Round 11
// baseline (298.026 us; speedup 1.0000x reference)
//
#include <hip/hip_runtime.h>

typedef __bf16 bf16;
typedef __bf16 bf16x4 __attribute__((ext_vector_type(4)));
typedef __bf16 bf16x8 __attribute__((ext_vector_type(8)));
typedef float f32x4 __attribute__((ext_vector_type(4)));

#define NB 4
#define NS 2048
#define ND 1024
#define NH 16
#define HD 64

// 0.125 (1/sqrt(64)) * log2(e): folded into Q so attn uses raw exp2
#define QSCALE 0.18033688f

__device__ __forceinline__ void gload_lds16(const void* g, void* l) {
  __builtin_amdgcn_global_load_lds(
      (const __attribute__((address_space(1))) void*)g,
      (__attribute__((address_space(3))) void*)l, 16, 0, 0);
}

__device__ __forceinline__ float fast_exp2(float x) {
#if __has_builtin(__builtin_amdgcn_exp2f)
  return __builtin_amdgcn_exp2f(x);
#else
  return exp2f(x);
#endif
}

// ---- merged prep: fp32->bf16 cvt of x  +  4x weight transpose-cvt ----
__global__ __launch_bounds__(256) void k_prep(
    const float* __restrict__ x, bf16* __restrict__ xb,
    const float* __restrict__ wq, const float* __restrict__ wk,
    const float* __restrict__ wv, const float* __restrict__ wo,
    bf16* __restrict__ wqkvT, bf16* __restrict__ woT) {
  __shared__ float t[32][33];
  const int bid = blockIdx.x, tid = threadIdx.x;
  if (bid < 8192) {
    size_t i = ((size_t)bid * 256 + tid) * 4;
    float4 v = *(const float4*)(x + i);
    bf16x4 o = {(__bf16)v.x, (__bf16)v.y, (__bf16)v.z, (__bf16)v.w};
    *(bf16x4*)(xb + i) = o;
    return;
  }
  const int r = bid - 8192;
  const int z = r >> 10;               // 0..3: wq, wk, wv, wo
  const int bx = r & 31, by = (r >> 5) & 31;
  const float* src = z == 0 ? wq : z == 1 ? wk : z == 2 ? wv : wo;
  bf16* dst = z < 3 ? wqkvT + (size_t)z * 1048576 : woT;
  const int tx = tid & 31, ty = tid >> 5;  // (32, 8) layout
  const int xx = bx * 32 + tx;
  const int yy = by * 32 + ty;
#pragma unroll
  for (int j = 0; j < 4; ++j)
    t[ty + j * 8][tx] = src[(size_t)(yy + j * 8) * 1024 + xx];
  __syncthreads();
  const int x2 = by * 32 + tx;
  const int y2 = bx * 32 + ty;
#pragma unroll
  for (int j = 0; j < 4; ++j)
    dst[(size_t)(y2 + j * 8) * 1024 + x2] = (__bf16)t[tx][ty + j * 8];
}

// --- bf16 V natural [B,S,H,64] -> V^T [B,H,64,S] (coalesced both sides) ---
__global__ __launch_bounds__(256) void k_vT(const bf16* __restrict__ V,
                                            bf16* __restrict__ Vt) {
  __shared__ bf16 t[64][72];
  int tid = threadIdx.x;
  int bh = blockIdx.x >> 5, st = blockIdx.x & 31;
  int b = bh >> 4, h = bh & 15;
  const bf16* src = V + ((size_t)b * NS + st * 64) * ND + h * HD;
#pragma unroll
  for (int rep = 0; rep < 2; ++rep) {
    int idx = rep * 256 + tid;
    int r = idx >> 3, c8 = (idx & 7) * 8;
    *(bf16x8*)&t[r][c8] = *(const bf16x8*)(src + (size_t)r * ND + c8);
  }
  __syncthreads();
  bf16* dst = Vt + (size_t)bh * HD * NS + st * 64;
#pragma unroll
  for (int rep = 0; rep < 2; ++rep) {
    int idx = rep * 256 + tid;
    int d = idx >> 3, s8 = (idx & 7) * 8;
    bf16x8 v;
#pragma unroll
    for (int j = 0; j < 8; ++j) {  // j-rotation keeps LDS reads bank-balanced
      int jj = (j + tid) & 7;
      v[jj] = t[s8 + jj][d];
    }
    *(bf16x8*)(dst + (size_t)d * NS + s8) = v;
  }
}

// --- 256x128 8-wave bf16 GEMM mainloop, plain 2-phase (R4, best measured) --
__device__ __forceinline__ void gemm256_mainloop(const bf16* __restrict__ A,
                                                 const bf16* __restrict__ BT,
                                                 int bm, int bn, bf16* As,
                                                 bf16* Bs, f32x4 acc[4][4]) {
  const int tid = threadIdx.x;
  const int w = tid >> 6, lane = tid & 63, quad = lane >> 4, l15 = lane & 15;
  const int l7 = l15 & 7, l8 = lane >> 3;
  const int wr = w >> 1, wc = w & 1;
  const int gsw = ((lane & 7) ^ l8) * 8;
  const bf16* gaw = A + (size_t)(bm * 256 + w * 8 + l8) * 1024 + gsw;
  const bf16* gbw = BT + (size_t)(bn * 128 + w * 8 + l8) * 1024 + gsw;
  bf16* daw = As + w * 512;  // wave-uniform base; HW adds lane*16B
  bf16* dbw = Bs + w * 512;
  int aoff[4][2], boff[4][2];
#pragma unroll
  for (int mi = 0; mi < 4; ++mi)
#pragma unroll
    for (int ks = 0; ks < 2; ++ks)
      aoff[mi][ks] =
          (wr * 64 + mi * 16 + l15) * 64 + (((ks * 4 + quad) ^ l7) * 8);
#pragma unroll
  for (int ni = 0; ni < 4; ++ni)
#pragma unroll
    for (int ks = 0; ks < 2; ++ks)
      boff[ni][ks] =
          (wc * 64 + ni * 16 + l15) * 64 + (((ks * 4 + quad) ^ l7) * 8);

  // prologue: stage K-tile 0 into buffer 0
#pragma unroll
  for (int ri = 0; ri < 4; ++ri)
    gload_lds16(gaw + (size_t)(ri * 64) * 1024, daw + ri * 4096);
#pragma unroll
  for (int ri = 0; ri < 2; ++ri)
    gload_lds16(gbw + (size_t)(ri * 64) * 1024, dbw + ri * 4096);

  for (int kt = 0; kt < 16; ++kt) {
    const int buf = kt & 1;
    __syncthreads();  // own kt-loads drained; all reads of buf^1 done
    if (kt + 1 < 16) {
      const bf16* ga = gaw + (kt + 1) * 64;
      const bf16* gb = gbw + (kt + 1) * 64;
      bf16* da = daw + (buf ^ 1) * 16384;
      bf16* db = dbw + (buf ^ 1) * 8192;
#pragma unroll
      for (int ri = 0; ri < 4; ++ri)
        gload_lds16(ga + (size_t)(ri * 64) * 1024, da + ri * 4096);
#pragma unroll
      for (int ri = 0; ri < 2; ++ri)
        gload_lds16(gb + (size_t)(ri * 64) * 1024, db + ri * 4096);
    }
    const bf16* a_ = As + buf * 16384;
    const bf16* b_ = Bs + buf * 8192;
#pragma unroll
    for (int ks = 0; ks < 2; ++ks) {
      bf16x8 av[4], bv[4];
#pragma unroll
      for (int i = 0; i < 4; ++i)
        av[i] = *(const bf16x8*)(a_ + aoff[i][ks]);
#pragma unroll
      for (int i = 0; i < 4; ++i)
        bv[i] = *(const bf16x8*)(b_ + boff[i][ks]);
#pragma unroll
      for (int mi = 0; mi < 4; ++mi)
#pragma unroll
        for (int ni = 0; ni < 4; ++ni)
          acc[mi][ni] = __builtin_amdgcn_mfma_f32_16x16x32_bf16(
              av[mi], bv[ni], acc[mi][ni], 0, 0, 0);
    }
  }
  __syncthreads();  // epilogue reuses the mainloop LDS
}

// QKV projection: Q (pre-scaled), K, V all stored natural [B,S,H,64]
__global__ __launch_bounds__(512, 2) void k_gemm_qkv(
    const bf16* __restrict__ A, const bf16* __restrict__ BT,
    const float* __restrict__ bq, const float* __restrict__ bk,
    const float* __restrict__ bv, bf16* __restrict__ Q, bf16* __restrict__ K,
    bf16* __restrict__ V) {
  __shared__ alignas(16) char smem[98304];
  bf16* As = (bf16*)smem;            // 2 x 16384 elems
  bf16* Bs = (bf16*)(smem + 65536);  // 2 x 8192 elems
  f32x4 acc[4][4] = {};
  const int bm = blockIdx.y, bn = blockIdx.x;
  gemm256_mainloop(A, BT, bm, bn, As, Bs, acc);
  const int tid = threadIdx.x;
  const int w = tid >> 6, lane = tid & 63, quad = lane >> 4, l15 = lane & 15;
  const int wr = w >> 1, wc = w & 1;
  bf16* sEw = (bf16*)smem + w * 4608;  // per-wave [64][72]
  const int colbase = bn * 128 + wc * 64;  // multiple of 64 -> wave-uniform
  const int which = colbase >> 10;
  const int nnbase = colbase & 1023;
  const float* bias = which == 0 ? bq : which == 1 ? bk : bv;
  bf16* dst = which == 0 ? Q : which == 1 ? K : V;
  const float scl = which == 0 ? QSCALE : 1.f;
  const int rowbase = bm * 256 + wr * 64;
#pragma unroll
  for (int ni = 0; ni < 4; ++ni) {
    float bb = bias[nnbase + ni * 16 + l15];
#pragma unroll
    for (int mi = 0; mi < 4; ++mi)
#pragma unroll
      for (int r = 0; r < 4; ++r)
        sEw[(mi * 16 + quad * 4 + r) * 72 + ni * 16 + l15] =
            (__bf16)((acc[mi][ni][r] + bb) * scl);
  }
  // per-wave buffer: in-wave LDS ordering suffices, no barrier
  const int l8 = lane >> 3, g8 = (lane & 7) * 8;
#pragma unroll
  for (int i = 0; i < 8; ++i) {
    int row = i * 8 + l8;
    bf16x8 vv = *(const bf16x8*)(sEw + row * 72 + g8);
    *(bf16x8*)(dst + (size_t)(rowbase + row) * 1024 + nnbase + g8) = vv;
  }
}

// --- fused out-projection + LayerNorm: [8192][1024]x[1024][1024] + LN ---
// BM=32 x BN=1024 (full rows) per block, grid 256 = 1 block/CU exactly.
// BK=32 double-buffered: A 32x32 (2KB) + B 1024x32 (64KB) x2 = 132 KiB LDS.
// B = woT is L2-resident (2MB/XCD); kernel is L2-BW-bound on staging
// (~64KB/step vs 620 cyc MFMA), so the 1-blk/CU barrier drain IS the
// staging wait - the R4-R6 drain penalty doesn't apply. With 64 B LDS rows,
// row-parity x granule(=quad) makes fragment reads conflict-free with NO
// swizzle: linear staging, linear reads. Epilogue: bias into fp32 acc ->
// 16-lane shfl row-partials -> cross-wave LDS reduce (32 rows) -> normalize
// in-register -> proven [32][68] float4 staged store to fp32 out.
// Removes k_ln + 1 boundary + the Yb intermediate (32 MB traffic).
__global__ __launch_bounds__(512) void k_gemm_out_ln(
    const bf16* __restrict__ A, const bf16* __restrict__ BT,
    const float* __restrict__ bo, const float* __restrict__ g,
    const float* __restrict__ beta, float* __restrict__ out) {
  __shared__ alignas(16) char smem[135168];
  bf16* As = (bf16*)smem;           // 2 x 1024 elems  ([32][32] per buf)
  bf16* Bs = (bf16*)(smem + 4096);  // 2 x 32768 elems ([1024][32] per buf)
  const int tid = threadIdx.x;
  const int w = tid >> 6, lane = tid & 63, quad = lane >> 4, l15 = lane & 15;
  const int lrow = lane >> 2, lcol = (lane & 3) * 8;  // staging lane map
  const int rowbase = blockIdx.x * 32;

  f32x4 acc[2][8] = {};

  // stage K-tile kt into slot: each wave 8 B-issues; waves 0,1 one A-issue.
  auto stage = [&](int kt, int slot) {
#pragma unroll
    for (int i = 0; i < 8; ++i) {
      const int r0 = (w * 8 + i) * 16;  // 16 B-rows per 1024B issue
      gload_lds16(BT + (size_t)(r0 + lrow) * 1024 + kt * 32 + lcol,
                  Bs + slot * 32768 + r0 * 32);
    }
    if (w < 2)
      gload_lds16(A + (size_t)(rowbase + w * 16 + lrow) * 1024 + kt * 32 +
                      lcol,
                  As + slot * 1024 + w * 512);
  };

  stage(0, 0);
  for (int kt = 0; kt < 32; ++kt) {
    const int buf = kt & 1;
    __syncthreads();  // own kt-loads drained; all reads of buf^1 done
    if (kt + 1 < 32) stage(kt + 1, buf ^ 1);
    const bf16* a_ = As + buf * 1024;
    const bf16* b_ = Bs + buf * 32768;
    bf16x8 av[2], bv[8];
#pragma unroll
    for (int mi = 0; mi < 2; ++mi)
      av[mi] = *(const bf16x8*)(a_ + (mi * 16 + l15) * 32 + quad * 8);
#pragma unroll
    for (int ni = 0; ni < 8; ++ni)
      bv[ni] =
          *(const bf16x8*)(b_ + (size_t)(w * 128 + ni * 16 + l15) * 32 +
                           quad * 8);
#pragma unroll
    for (int mi = 0; mi < 2; ++mi)
#pragma unroll
      for (int ni = 0; ni < 8; ++ni)
        acc[mi][ni] = __builtin_amdgcn_mfma_f32_16x16x32_bf16(
            av[mi], bv[ni], acc[mi][ni], 0, 0, 0);
  }
  __syncthreads();  // epilogue reuses the mainloop LDS

  float* redS = (float*)smem;            // [8][32] row sums
  float* redQ = (float*)(smem + 1024);   // [8][32] row sumsq
  float* mustd = (float*)(smem + 2048);  // [32][2] (mu, rstd)

  // bias into acc -> y (fp32, better than the old bf16-Yb path)
  float bb[8];
#pragma unroll
  for (int ni = 0; ni < 8; ++ni) bb[ni] = bo[w * 128 + ni * 16 + l15];
#pragma unroll
  for (int mi = 0; mi < 2; ++mi)
#pragma unroll
    for (int ni = 0; ni < 8; ++ni)
#pragma unroll
      for (int r = 0; r < 4; ++r) acc[mi][ni][r] += bb[ni];

  // per-wave row partials over this wave's 128 cols (16-lane shfl groups)
#pragma unroll
  for (int mi = 0; mi < 2; ++mi)
#pragma unroll
    for (int r = 0; r < 4; ++r) {
      float sm = 0.f, sq = 0.f;
#pragma unroll
      for (int ni = 0; ni < 8; ++ni) {
        float v = acc[mi][ni][r];
        sm += v;
        sq += v * v;
      }
#pragma unroll
      for (int off = 1; off < 16; off <<= 1) {
        sm += __shfl_xor(sm, off, 64);
        sq += __shfl_xor(sq, off, 64);
      }
      if (l15 == 0) {
        int row = mi * 16 + quad * 4 + r;
        redS[w * 32 + row] = sm;
        redQ[w * 32 + row] = sq;
      }
    }
  __syncthreads();
  if (tid < 32) {
    float sm = 0.f, sq = 0.f;
#pragma unroll
    for (int ww = 0; ww < 8; ++ww) {
      sm += redS[ww * 32 + tid];
      sq += redQ[ww * 32 + tid];
    }
    float mu = sm * (1.f / 1024.f);
    float var = sq * (1.f / 1024.f) - mu * mu;
    mustd[tid * 2] = mu;
    mustd[tid * 2 + 1] = rsqrtf(var + 1e-12f);
  }
  __syncthreads();

  float gg[8], be[8];
#pragma unroll
  for (int ni = 0; ni < 8; ++ni) {
    gg[ni] = g[w * 128 + ni * 16 + l15];
    be[ni] = beta[w * 128 + ni * 16 + l15];
  }
  float mur[2][4], rsr[2][4];
#pragma unroll
  for (int mi = 0; mi < 2; ++mi)
#pragma unroll
    for (int r = 0; r < 4; ++r) {
      int row = mi * 16 + quad * 4 + r;
      mur[mi][r] = mustd[row * 2];
      rsr[mi][r] = mustd[row * 2 + 1];
    }

  // staged fp32 write, two 64-col halves (proven [32][68] pattern)
  float* sEw = (float*)(smem + 4096) + w * 2176;  // per-wave [32][68]
  const int l4 = lane >> 4, c4 = (lane & 15) * 4;
#pragma unroll
  for (int hf = 0; hf < 2; ++hf) {
#pragma unroll
    for (int mi = 0; mi < 2; ++mi)
#pragma unroll
      for (int nj = 0; nj < 4; ++nj) {
        const int ni = hf * 4 + nj;
#pragma unroll
        for (int r = 0; r < 4; ++r)
          sEw[(mi * 16 + quad * 4 + r) * 68 + nj * 16 + l15] =
              (acc[mi][ni][r] - mur[mi][r]) * rsr[mi][r] * gg[ni] + be[ni];
      }
    // per-wave buffer; in-wave ds ordering makes this safe
#pragma unroll
    for (int i = 0; i < 8; ++i) {
      int row = i * 4 + l4;
      float4 v = *(const float4*)(sEw + row * 68 + c4);
      *(float4*)(out + (size_t)(rowbase + row) * 1024 + w * 128 + hf * 64 +
                 c4) = v;
    }
  }
}

// ---------------- flash attention v7 (proven 90.2 us) ----------------
__global__ __launch_bounds__(256, 4) void k_attn(const bf16* __restrict__ Qg,
                                                 const bf16* __restrict__ Kg,
                                                 const bf16* __restrict__ VtG,
                                                 bf16* __restrict__ O) {
  __shared__ alignas(16) char smem[40960];
  bf16* sK = (bf16*)smem;              // 2 x 4096 elems
  bf16* sVt = (bf16*)(smem + 16384);   // 2 x 4096 elems
  const int tid = threadIdx.x;
  const int w = tid >> 6, lane = tid & 63, quad = lane >> 4, l15 = lane & 15;
  const int l7 = l15 & 7, l8 = lane >> 3;
  const int sw = (l15 >> 1) & 3;  // row-parity-decorrelated granule swizzle
  const int bh = blockIdx.x & 63;   // XCD-friendly: bh mod 8 fixed per bh
  const int qt = blockIdx.x >> 6;   // 0..15
  const int b = bh >> 4, h = bh & 15;
  const bf16* Qh = Qg + (size_t)b * NS * ND + h * HD;
  const bf16* Kh = Kg + (size_t)b * NS * ND + h * HD;
  const bf16* Vh = VtG + (size_t)bh * HD * NS;  // [64][2048]
  bf16* Pw = (bf16*)(smem + 32768) + w * 1024;  // per-wave [32][32] swizzled

  const int q0 = qt * 128 + w * 32;
  // Q B-fragments (pre-scaled at QKV epilogue), registers for whole kernel
  bf16x8 qb[2][2];
#pragma unroll
  for (int ni = 0; ni < 2; ++ni)
#pragma unroll
    for (int ks = 0; ks < 2; ++ks)
      qb[ni][ks] = *(const bf16x8*)(Qh + (size_t)(q0 + ni * 16 + l15) * ND +
                                    ks * 32 + quad * 8);

  // staging addresses (XOR-granule swizzle g^=row&7, lane-linear LDS dest)
  const int gsw = ((lane & 7) ^ l8) * 8;
  const bf16* gk = Kh + (size_t)(w * 8 + l8) * ND + gsw;
  const bf16* gv = Vh + (size_t)(w * 8 + l8) * NS + gsw;
  bf16* dk = sK + w * 512;
  bf16* dv = sVt + w * 512;

  f32x4 o_acc[4][2] = {};  // O^T: row d=mi*16+quad*4+r, col q=ni*16+l15
  float l_run[2] = {0.f, 0.f};  // lane-local partial denominators

  // chunk-invariant swizzled fragment offsets
  int offA[4][2];
#pragma unroll
  for (int mi = 0; mi < 4; ++mi)
#pragma unroll
    for (int ks = 0; ks < 2; ++ks)
      offA[mi][ks] = (mi * 16 + l15) * 64 + (((ks * 4 + quad) ^ l7) * 8);
  // P tile [32 q][32 k] bf16, 64 B rows, 4 granules of 16 B, XOR sw
  int offP[2], wbase[2], wg[2];
#pragma unroll
  for (int ni = 0; ni < 2; ++ni) {
    offP[ni] = (ni * 16 + l15) * 32 + ((quad ^ sw) * 8);
    wbase[ni] = (ni * 16 + l15) * 32 + (quad & 1) * 4;
  }
#pragma unroll
  for (int m2 = 0; m2 < 2; ++m2)
    wg[m2] = (((m2 * 2 + (quad >> 1)) ^ sw) * 8);

  // prologue: stage chunk 0 into buffer 0
  gload_lds16(gk, dk);
  gload_lds16(gk + 32 * ND, dk + 2048);
  gload_lds16(gv, dv);
  gload_lds16(gv + 32 * NS, dv + 2048);

  for (int it = 0; it < NS / 64; ++it) {
    const int buf = (it & 1) * 4096;
    __syncthreads();  // drains own chunk-it loads; all buf^1 reads done
    if (it + 1 < NS / 64) {
      const int nbuf = 4096 - buf;
      const bf16* gk1 = gk + (size_t)(it + 1) * 64 * ND;
      const bf16* gv1 = gv + (it + 1) * 64;
      gload_lds16(gk1, dk + nbuf);
      gload_lds16(gk1 + 32 * ND, dk + nbuf + 2048);
      gload_lds16(gv1, dv + nbuf);
      gload_lds16(gv1 + 32 * NS, dv + nbuf + 2048);
    }

#pragma unroll
    for (int hf = 0; hf < 2; ++hf) {  // 32-key half: keys hf*32..hf*32+31
      // S^T = K Q^T for mi = 2*hf + m2; exp2 + P-write immediately
#pragma unroll
      for (int m2 = 0; m2 < 2; ++m2) {
        const int mi = 2 * hf + m2;
        f32x4 s[2] = {};
#pragma unroll
        for (int ks = 0; ks < 2; ++ks) {
          bf16x8 ak = *(const bf16x8*)(sK + buf + offA[mi][ks]);
#pragma unroll
          for (int ni = 0; ni < 2; ++ni)
            s[ni] = __builtin_amdgcn_mfma_f32_16x16x32_bf16(ak, qb[ni][ks],
                                                            s[ni], 0, 0, 0);
        }
#pragma unroll
        for (int ni = 0; ni < 2; ++ni) {
#pragma unroll
          for (int r = 0; r < 4; ++r) {
            s[ni][r] = fast_exp2(s[ni][r]);
            l_run[ni] += s[ni][r];
          }
          bf16x4 p = {(__bf16)s[ni][0], (__bf16)s[ni][1], (__bf16)s[ni][2],
                      (__bf16)s[ni][3]};
          *(bf16x4*)(Pw + wbase[ni] + wg[m2]) = p;
        }
      }

      // O^T += V^T P^T for this 32-key half (ks = hf); per-wave P, no barrier
      bf16x8 pb[2];
#pragma unroll
      for (int ni = 0; ni < 2; ++ni)
        pb[ni] = *(const bf16x8*)(Pw + offP[ni]);
#pragma unroll
      for (int mi = 0; mi < 4; ++mi) {
        bf16x8 av = *(const bf16x8*)(sVt + buf + offA[mi][hf]);
#pragma unroll
        for (int ni = 0; ni < 2; ++ni)
          o_acc[mi][ni] = __builtin_amdgcn_mfma_f32_16x16x32_bf16(
              av, pb[ni], o_acc[mi][ni], 0, 0, 0);
      }
    }
  }

  // epilogue: finish denominator reduction, write attn_out [B,S,H*64] bf16
#pragma unroll
  for (int ni = 0; ni < 2; ++ni) {
    float l = l_run[ni];
    l += __shfl_xor(l, 16, 64);
    l += __shfl_xor(l, 32, 64);
    float inv = 1.f / l;
    int q = q0 + ni * 16 + l15;
    size_t orow = ((size_t)b * NS + q) * 1024 + h * 64;
#pragma unroll
    for (int mi = 0; mi < 4; ++mi) {
      bf16x4 ov = {
          (__bf16)(o_acc[mi][ni][0] * inv), (__bf16)(o_acc[mi][ni][1] * inv),
          (__bf16)(o_acc[mi][ni][2] * inv), (__bf16)(o_acc[mi][ni][3] * inv)};
      *(bf16x4*)(O + orow + mi * 16 + quad * 4) = ov;
    }
  }
}

extern "C" void kernel_launch(void* const* d_in, const int* in_sizes, int n_in,
                              void* d_out, int out_size, void* d_ws,
                              size_t ws_size, hipStream_t stream) {
  const float* x = (const float*)d_in[0];
  const float* wq = (const float*)d_in[1];
  const float* bq = (const float*)d_in[2];
  const float* wk = (const float*)d_in[3];
  const float* bk = (const float*)d_in[4];
  const float* wv = (const float*)d_in[5];
  const float* bv = (const float*)d_in[6];
  const float* wo = (const float*)d_in[7];
  const float* bo = (const float*)d_in[8];
  const float* ln_g = (const float*)d_in[9];
  const float* ln_b = (const float*)d_in[10];
  float* out = (float*)d_out;

  char* ws = (char*)d_ws;
  bf16* xb = (bf16*)ws;          ws += 16777216;   // [8192][1024]
  bf16* wqkvT = (bf16*)ws;       ws += 6291456;    // [3072][1024]
  bf16* woT = (bf16*)ws;         ws += 2097152;    // [1024][1024]
  bf16* Qh = (bf16*)ws;          ws += 16777216;   // [B,S,H,64] (pre-scaled)
  bf16* Kh = (bf16*)ws;          ws += 16777216;   // [B,S,H,64]
  bf16* Vh = (bf16*)ws;          ws += 16777216;   // [B,S,H,64]
  bf16* Vt = (bf16*)ws;          ws += 16777216;   // [B,H,64,S] (transposed)
  bf16* AOb = (bf16*)ws;         ws += 16777216;   // [8192][1024]

  k_prep<<<12288, 256, 0, stream>>>(x, xb, wq, wk, wv, wo, wqkvT, woT);

  k_gemm_qkv<<<dim3(24, 32), 512, 0, stream>>>(xb, wqkvT, bq, bk, bv, Qh, Kh,
                                               Vh);
  k_vT<<<NB * NH * 32, 256, 0, stream>>>(Vh, Vt);
  k_attn<<<NB * NH * (NS / 128), 256, 0, stream>>>(Qh, Kh, Vt, AOb);
  k_gemm_out_ln<<<256, 512, 0, stream>>>(AOb, woT, bo, ln_g, ln_b, out);
}